// Round 4
// baseline (478.880 us; speedup 1.0000x reference)
//
#include <hip/hip_runtime.h>

#define N_NODES   100000
#define D_DIM     16
#define NFILT     8
#define KOUT      (D_DIM * NFILT)   // 128
#define NNZ_CNT   1600000
#define NXCD      8
#define NBUCK     (NXCD * N_NODES)  // 800000 flat (xcd, row) buckets

#define S1_BLOCK  1024
#define S1_NBLK   ((NBUCK + S1_BLOCK - 1) / S1_BLOCK)   // 782

// w_wav[n,f] = t^(2^f) - t^(2^(f+1)),  t = exp(-eig[n]); exact repeated squaring
__global__ void wav_kernel(const float* __restrict__ eig, float* __restrict__ w_wav) {
    int n = blockIdx.x * blockDim.x + threadIdx.x;
    if (n >= N_NODES) return;
    float cur = expf(-eig[n]);
    float w[NFILT];
#pragma unroll
    for (int f = 0; f < NFILT; ++f) {
        float nx = cur * cur;
        w[f] = cur - nx;
        cur = nx;
    }
    float4* p = (float4*)(w_wav + (size_t)n * NFILT);
    p[0] = make_float4(w[0], w[1], w[2], w[3]);
    p[1] = make_float4(w[4], w[5], w[6], w[7]);
}

// Pass 1: LTx[c,d] += v[e] * x[r,d]   (16 threads per edge; LTx is 6.4MB, L2-resident)
__global__ void scatter1_kernel(const float* __restrict__ x,
                                const int* __restrict__ rows,
                                const int* __restrict__ cols,
                                const float* __restrict__ v,
                                float* __restrict__ LTx) {
    long long idx = (long long)blockIdx.x * blockDim.x + threadIdx.x;
    if (idx >= (long long)NNZ_CNT * D_DIM) return;
    int e = (int)(idx >> 4);
    int d = (int)(idx & 15);
    int r = rows[e];
    int c = cols[e];
    float val = v[e] * x[(size_t)r * D_DIM + d];
    atomicAdd(LTx + (size_t)c * D_DIM + d, val);
}

// --- CSR build with per-XCD regions: bucket = (blockIdx&7)*N + row ---
// blockIdx&7 approximates the physical XCD (round-robin dispatch); correctness
// does not depend on the mapping, only that hist and permute agree per edge.

__global__ void hist_kernel(const int* __restrict__ rows, int* __restrict__ counts) {
    int e = blockIdx.x * blockDim.x + threadIdx.x;
    if (e >= NNZ_CNT) return;
    int b = (blockIdx.x & (NXCD - 1)) * N_NODES + rows[e];
    atomicAdd(&counts[b], 1);
}

// in-place per-block exclusive scan over counts[NBUCK] -> offs (same array) + block sums
__global__ void scan1_kernel(int* __restrict__ offs, int* __restrict__ blocksums) {
    __shared__ int s[S1_BLOCK];
    int tid = threadIdx.x;
    int i = blockIdx.x * S1_BLOCK + tid;
    int v = (i < NBUCK) ? offs[i] : 0;
    s[tid] = v;
    __syncthreads();
    for (int off = 1; off < S1_BLOCK; off <<= 1) {
        int t = (tid >= off) ? s[tid - off] : 0;
        __syncthreads();
        s[tid] += t;
        __syncthreads();
    }
    if (i < NBUCK) offs[i] = s[tid] - v;   // block-local exclusive
    if (tid == S1_BLOCK - 1) blocksums[blockIdx.x] = s[tid];
}

// single block: exclusive scan of S1_NBLK (<=1024) block sums
__global__ void scan2_kernel(const int* __restrict__ blocksums, int* __restrict__ blockoffs) {
    __shared__ int s[S1_BLOCK];
    int tid = threadIdx.x;
    int v = (tid < S1_NBLK) ? blocksums[tid] : 0;
    s[tid] = v;
    __syncthreads();
    for (int off = 1; off < S1_BLOCK; off <<= 1) {
        int t = (tid >= off) ? s[tid - off] : 0;
        __syncthreads();
        s[tid] += t;
        __syncthreads();
    }
    if (tid < S1_NBLK) blockoffs[tid] = s[tid] - v;
}

__global__ void scan3_kernel(int* __restrict__ offs, const int* __restrict__ blockoffs) {
    int i = blockIdx.x * S1_BLOCK + threadIdx.x;
    if (i >= NBUCK) return;
    offs[i] += blockoffs[blockIdx.x];
}

// permute edges into (xcd, row)-grouped order; offs doubles as the cursor.
// After this kernel, offs[b] = END of segment b (start = offs[b-1], offs[-1]=0).
__global__ void permute_kernel(const int* __restrict__ rows,
                               const int* __restrict__ cols,
                               const float* __restrict__ v,
                               int* __restrict__ offs,
                               int2* __restrict__ ep) {
    int e = blockIdx.x * blockDim.x + threadIdx.x;
    if (e >= NNZ_CNT) return;
    int b = (blockIdx.x & (NXCD - 1)) * N_NODES + rows[e];
    int pos = atomicAdd(&offs[b], 1);
    ep[pos] = make_int2(cols[e], __float_as_int(v[e]));
}

// Pass 2 gather: one wave per row; lane owns outputs (lane) and (lane+64).
// Walk the 8 per-XCD segments of this row.
__global__ __launch_bounds__(256) void gather2_kernel(const int* __restrict__ offs,
                                                      const int2* __restrict__ ep,
                                                      const float* __restrict__ LTx,
                                                      const float* __restrict__ wav,
                                                      float* __restrict__ out) {
    int wave = (int)(((long long)blockIdx.x * blockDim.x + threadIdx.x) >> 6);
    if (wave >= N_NODES) return;
    int lane = threadIdx.x & 63;
    int r = wave;
    int d0 = lane >> 3;        // 0..7
    int f  = lane & 7;         // 0..7
    int d1 = d0 + 8;           // 8..15
    float acc0 = 0.f, acc1 = 0.f;
#pragma unroll
    for (int x = 0; x < NXCD; ++x) {
        int fi = x * N_NODES + r;
        int start = (fi == 0) ? 0 : offs[fi - 1];
        int end   = offs[fi];
        int i = start;
        for (; i + 2 <= end; i += 2) {
            int2 e0 = ep[i], e1 = ep[i + 1];
            float w0 = wav[(size_t)e0.x * NFILT + f];
            float w1 = wav[(size_t)e1.x * NFILT + f];
            float l00 = LTx[(size_t)e0.x * D_DIM + d0], l01 = LTx[(size_t)e0.x * D_DIM + d1];
            float l10 = LTx[(size_t)e1.x * D_DIM + d0], l11 = LTx[(size_t)e1.x * D_DIM + d1];
            float vw0 = __int_as_float(e0.y) * w0;
            float vw1 = __int_as_float(e1.y) * w1;
            acc0 = fmaf(vw0, l00, acc0); acc1 = fmaf(vw0, l01, acc1);
            acc0 = fmaf(vw1, l10, acc0); acc1 = fmaf(vw1, l11, acc1);
        }
        if (i < end) {
            int2 e = ep[i];
            float w = wav[(size_t)e.x * NFILT + f];
            float vw = __int_as_float(e.y) * w;
            acc0 = fmaf(vw, LTx[(size_t)e.x * D_DIM + d0], acc0);
            acc1 = fmaf(vw, LTx[(size_t)e.x * D_DIM + d1], acc1);
        }
    }
    out[(size_t)r * KOUT + lane]      = acc0;
    out[(size_t)r * KOUT + 64 + lane] = acc1;
}

extern "C" void kernel_launch(void* const* d_in, const int* in_sizes, int n_in,
                              void* d_out, int out_size, void* d_ws, size_t ws_size,
                              hipStream_t stream) {
    const float* x      = (const float*)d_in[0];
    const int*   L_rows = (const int*)  d_in[1];
    const int*   L_cols = (const int*)  d_in[2];
    const float* L_v    = (const float*)d_in[3];
    const float* eig    = (const float*)d_in[4];
    float* out = (float*)d_out;

    // workspace layout (~26 MB)
    float* LTx       = (float*)d_ws;                          // [N*16]   6.4 MB
    float* wav       = LTx + (size_t)N_NODES * D_DIM;         // [N*8]    3.2 MB
    int*   offs      = (int*)(wav + (size_t)N_NODES * NFILT); // [8*N]    3.2 MB (counts->offsets->cursors)
    int*   blocksums = offs + NBUCK;                          // [1024]
    int*   blockoffs = blocksums + S1_BLOCK;                  // [1024]
    int2*  ep        = (int2*)(blockoffs + S1_BLOCK);         // [NNZ]    12.8 MB (8B-aligned: offset is even)

    hipMemsetAsync(LTx, 0, (size_t)N_NODES * D_DIM * sizeof(float), stream);
    hipMemsetAsync(offs, 0, (size_t)NBUCK * sizeof(int), stream);

    wav_kernel<<<(N_NODES + 255) / 256, 256, 0, stream>>>(eig, wav);

    // CSR build with per-XCD regions
    hist_kernel<<<(NNZ_CNT + 255) / 256, 256, 0, stream>>>(L_rows, offs);
    scan1_kernel<<<S1_NBLK, S1_BLOCK, 0, stream>>>(offs, blocksums);
    scan2_kernel<<<1, S1_BLOCK, 0, stream>>>(blocksums, blockoffs);
    scan3_kernel<<<S1_NBLK, S1_BLOCK, 0, stream>>>(offs, blockoffs);
    permute_kernel<<<(NNZ_CNT + 255) / 256, 256, 0, stream>>>(L_rows, L_cols, L_v, offs, ep);

    // Pass 1 (atomic scatter into L2-resident 6.4MB LTx)
    {
        long long total = (long long)NNZ_CNT * D_DIM;
        scatter1_kernel<<<(int)((total + 255) / 256), 256, 0, stream>>>(x, L_rows, L_cols, L_v, LTx);
    }
    // Pass 2 (gather, no atomics)
    {
        long long threads = (long long)N_NODES * 64;   // one wave per row
        gather2_kernel<<<(int)((threads + 255) / 256), 256, 0, stream>>>(offs, ep, LTx, wav, out);
    }
}